// Round 2
// baseline (1736.775 us; speedup 1.0000x reference)
//
#include <hip/hip_runtime.h>
#include <hip/hip_bf16.h>

#define TSTR 68          // LDS tile row stride in floats (16B aligned, odd in 16B quads)
#define SSTR 129         // sims LDS row stride

// codebook row norms, f64 accumulation for accuracy, deterministic
__global__ void rn_kernel(const float* __restrict__ cb, float* __restrict__ rn) {
    const int j = blockIdx.x;
    const int t = threadIdx.x;
    double a = 0.0;
#pragma unroll
    for (int m = 0; m < 8; ++m) {
        float f = cb[j * 512 + m * 64 + t];
        a += (double)f * (double)f;
    }
#pragma unroll
    for (int off = 32; off >= 1; off >>= 1)
        a += __shfl_down(a, off);
    if (t == 0) rn[j] = (float)sqrt(a);
}

__global__ __launch_bounds__(256, 2) void fused_kernel(
    const float* __restrict__ x, const float* __restrict__ cb,
    const float* __restrict__ W, const float* __restrict__ bias,
    const float* __restrict__ u, const float* __restrict__ v,
    const float* __restrict__ rn, float* __restrict__ out,
    size_t idx_off, size_t val_off)
{
    __shared__ __align__(16) float uA[128 * TSTR];   // x(64*68)+W(64*68) | reg tile(128*68) | sims(64*129)
    __shared__ __align__(16) float xeL[64 * TSTR];   // xe chunk [64][64]
    __shared__ float rnL[128];
    __shared__ int   idxL[64 * 3];

    const int tid = threadIdx.x;
    const int tlo = tid & 15;
    const int thi = tid >> 4;
    const int row0 = blockIdx.x << 6;

    if (tid < 128) rnL[tid] = rn[tid];

    const int srow = tid >> 2;          // staging: 0..63
    const int scol = (tid & 3) << 4;    // 0,16,32,48

    float m2[4][8];                      // sims accumulators: rows tlo+16i, regs thi+16j
#pragma unroll
    for (int i = 0; i < 4; ++i)
#pragma unroll
        for (int j = 0; j < 8; ++j) m2[i][j] = 0.f;
    float nacc = 0.f;                    // |xe_row|^2 for tid<64

    for (int dc = 0; dc < 8; ++dc) {
        float m1[4][4];                  // xe accumulators: rows thi+16i, dims tlo+16j
#pragma unroll
        for (int i = 0; i < 4; ++i)
#pragma unroll
            for (int j = 0; j < 4; ++j) m1[i][j] = 0.f;

        for (int kc = 0; kc < 8; ++kc) {
            __syncthreads();   // uA free (prev readers done)
            {
                const float4* gx = (const float4*)(x + (size_t)(row0 + srow) * 512 + kc * 64 + scol);
                const float4* gw = (const float4*)(W + (size_t)(dc * 64 + srow) * 512 + kc * 64 + scol);
                float4* dx = (float4*)&uA[srow * TSTR + scol];
                float4* dw = (float4*)&uA[64 * TSTR + srow * TSTR + scol];
#pragma unroll
                for (int m = 0; m < 4; ++m) { dx[m] = gx[m]; dw[m] = gw[m]; }
            }
            __syncthreads();
            float s1[4][4];              // per-k-chunk sub-accumulator (accuracy)
#pragma unroll
            for (int i = 0; i < 4; ++i)
#pragma unroll
                for (int j = 0; j < 4; ++j) s1[i][j] = 0.f;
#pragma unroll
            for (int kk = 0; kk < 16; ++kk) {
                float4 xa[4], wa[4];
#pragma unroll
                for (int i = 0; i < 4; ++i)
                    xa[i] = *(const float4*)&uA[(thi + 16 * i) * TSTR + (kk << 2)];
#pragma unroll
                for (int j = 0; j < 4; ++j)
                    wa[j] = *(const float4*)&uA[64 * TSTR + (tlo + 16 * j) * TSTR + (kk << 2)];
#pragma unroll
                for (int i = 0; i < 4; ++i)
#pragma unroll
                    for (int j = 0; j < 4; ++j) {
                        s1[i][j] = fmaf(xa[i].x, wa[j].x, s1[i][j]);
                        s1[i][j] = fmaf(xa[i].y, wa[j].y, s1[i][j]);
                        s1[i][j] = fmaf(xa[i].z, wa[j].z, s1[i][j]);
                        s1[i][j] = fmaf(xa[i].w, wa[j].w, s1[i][j]);
                    }
            }
#pragma unroll
            for (int i = 0; i < 4; ++i)
#pragma unroll
                for (int j = 0; j < 4; ++j) m1[i][j] += s1[i][j];
        }
        // bias + store xe chunk to LDS
#pragma unroll
        for (int j = 0; j < 4; ++j) {
            float bj = bias[dc * 64 + tlo + 16 * j];
#pragma unroll
            for (int i = 0; i < 4; ++i)
                xeL[(thi + 16 * i) * TSTR + tlo + 16 * j] = m1[i][j] + bj;
        }
        __syncthreads();
        // stage codebook tile [128][64] into uA; accumulate row norms from xeL
        {
            const float4* gr = (const float4*)(cb + (size_t)(tid >> 1) * 512 + dc * 64 + ((tid & 1) << 5));
            float4* dr = (float4*)&uA[(tid >> 1) * TSTR + ((tid & 1) << 5)];
#pragma unroll
            for (int m = 0; m < 8; ++m) dr[m] = gr[m];
        }
        if (tid < 64) {
#pragma unroll
            for (int dd = 0; dd < 16; ++dd) {
                float4 q = *(const float4*)&xeL[tid * TSTR + (dd << 2)];
                nacc = fmaf(q.x, q.x, nacc);
                nacc = fmaf(q.y, q.y, nacc);
                nacc = fmaf(q.z, q.z, nacc);
                nacc = fmaf(q.w, q.w, nacc);
            }
        }
        __syncthreads();
        // phase 2: sims partial over this d-chunk
        float s2[4][8];
#pragma unroll
        for (int i = 0; i < 4; ++i)
#pragma unroll
            for (int j = 0; j < 8; ++j) s2[i][j] = 0.f;
#pragma unroll
        for (int dd = 0; dd < 16; ++dd) {
            float4 xv[4], rv[8];
#pragma unroll
            for (int i = 0; i < 4; ++i)
                xv[i] = *(const float4*)&xeL[(tlo + 16 * i) * TSTR + (dd << 2)];
#pragma unroll
            for (int j = 0; j < 8; ++j)
                rv[j] = *(const float4*)&uA[(thi + 16 * j) * TSTR + (dd << 2)];
#pragma unroll
            for (int i = 0; i < 4; ++i)
#pragma unroll
                for (int j = 0; j < 8; ++j) {
                    s2[i][j] = fmaf(xv[i].x, rv[j].x, s2[i][j]);
                    s2[i][j] = fmaf(xv[i].y, rv[j].y, s2[i][j]);
                    s2[i][j] = fmaf(xv[i].z, rv[j].z, s2[i][j]);
                    s2[i][j] = fmaf(xv[i].w, rv[j].w, s2[i][j]);
                }
        }
#pragma unroll
        for (int i = 0; i < 4; ++i)
#pragma unroll
            for (int j = 0; j < 8; ++j) m2[i][j] += s2[i][j];
    }
    __syncthreads();
    // dump sims numerators to LDS
#pragma unroll
    for (int i = 0; i < 4; ++i)
#pragma unroll
        for (int j = 0; j < 8; ++j)
            uA[(tlo + 16 * i) * SSTR + thi + 16 * j] = m2[i][j];
    __syncthreads();

    if (tid < 64) {
        float xn = sqrtf(nacc);
        float b0 = -1e30f, b1 = -1e30f, b2 = -1e30f;
        int i0 = 0, i1 = 0, i2 = 0;
        for (int j = 0; j < 128; ++j) {
            float s = uA[tid * SSTR + j] / fmaxf(xn * rnL[j], 1e-8f);
            if (s > b0)      { b2 = b1; i2 = i1; b1 = b0; i1 = i0; b0 = s; i0 = j; }
            else if (s > b1) { b2 = b1; i2 = i1; b1 = s;  i1 = j; }
            else if (s > b2) { b2 = s;  i2 = j; }
        }
        const size_t g = (size_t)(row0 + tid);
        float* oi = out + idx_off + g * 3;
        oi[0] = (float)i0;
        oi[1] = (float)i1;
        oi[2] = (float)i2;
        float* ov = out + val_off + g * 3;
        ov[0] = b0;
        ov[1] = b1;
        ov[2] = b2;
        idxL[tid * 3 + 0] = i0; idxL[tid * 3 + 1] = i1; idxL[tid * 3 + 2] = i2;
    }
    __syncthreads();

    // adapted_centers = cb[idx] + u[t]*v  -> f32
    {
        const int arow = tid >> 2;       // 0..63
        const int seg  = tid & 3;        // 128-dim segment
#pragma unroll
        for (int tt = 0; tt < 3; ++tt) {
            const int idx = idxL[arow * 3 + tt];
            const float uu = u[tt];
            const float4* gr4 = (const float4*)(cb + (size_t)idx * 512 + seg * 128);
            const float4* gv4 = (const float4*)(v + seg * 128);
            float4* ob = (float4*)(out + ((size_t)(row0 + arow) * 3 + tt) * 512 + seg * 128);
#pragma unroll
            for (int c = 0; c < 32; ++c) {
                float4 rv = gr4[c];
                float4 vv = gv4[c];
                float4 o;
                o.x = fmaf(uu, vv.x, rv.x);
                o.y = fmaf(uu, vv.y, rv.y);
                o.z = fmaf(uu, vv.z, rv.z);
                o.w = fmaf(uu, vv.w, rv.w);
                ob[c] = o;
            }
        }
    }
}

extern "C" void kernel_launch(void* const* d_in, const int* in_sizes, int n_in,
                              void* d_out, int out_size, void* d_ws, size_t ws_size,
                              hipStream_t stream) {
    const float* x  = (const float*)d_in[0];
    const float* cb = (const float*)d_in[1];
    const float* W  = (const float*)d_in[2];
    const float* b  = (const float*)d_in[3];
    const float* u  = (const float*)d_in[4];
    const float* v  = (const float*)d_in[5];
    float* rn = (float*)d_ws;                        // 128 floats scratch
    float* out = (float*)d_out;

    const size_t B = (size_t)in_sizes[0] / 512;      // 131072
    const size_t val_off = (size_t)out_size - 3 * B; // top_k_values
    const size_t idx_off = (size_t)out_size - 6 * B; // top_k_indices

    hipLaunchKernelGGL(rn_kernel, dim3(128), dim3(64), 0, stream, cb, rn);
    hipLaunchKernelGGL(fused_kernel, dim3((unsigned)(B / 64)), dim3(256), 0, stream,
                       x, cb, W, b, u, v, rn, out, idx_off, val_off);
}

// Round 4
// 1643.763 us; speedup vs baseline: 1.0566x; 1.0566x over previous
//
#include <hip/hip_runtime.h>

#define TSTR 68          // uA tile row stride in floats (16B aligned)
#define XESTR 68         // xeL row stride (16B aligned) — verbatim round 2
#define SSTR 129         // sims LDS row stride

__device__ __forceinline__ unsigned long long pack_key(float s, int col) {
    unsigned u = __float_as_uint(s);
    unsigned m = (u & 0x80000000u) ? ~u : (u | 0x80000000u);
    return ((unsigned long long)m << 32) | (unsigned)(127 - col);
}
__device__ __forceinline__ float key_val(unsigned long long k) {
    unsigned m = (unsigned)(k >> 32);
    unsigned u = (m & 0x80000000u) ? (m ^ 0x80000000u) : ~m;
    return __uint_as_float(u);
}
__device__ __forceinline__ int key_col(unsigned long long k) {
    return 127 - (int)(k & 0xFFFFFFFFu);
}
__device__ __forceinline__ void ins3(unsigned long long x,
        unsigned long long &a0, unsigned long long &a1, unsigned long long &a2) {
    if (x > a0)      { a2 = a1; a1 = a0; a0 = x; }
    else if (x > a1) { a2 = a1; a1 = x; }
    else if (x > a2) { a2 = x; }
}

// codebook row norms, f64 accumulation — verbatim round 2 (validated)
__global__ void rn_kernel(const float* __restrict__ cb, float* __restrict__ rn) {
    const int j = blockIdx.x;
    const int t = threadIdx.x;
    double a = 0.0;
#pragma unroll
    for (int m = 0; m < 8; ++m) {
        float f = cb[j * 512 + m * 64 + t];
        a += (double)f * (double)f;
    }
#pragma unroll
    for (int off = 32; off >= 1; off >>= 1)
        a += __shfl_down(a, off);
    if (t == 0) rn[j] = (float)sqrt(a);
}

__global__ __launch_bounds__(256, 3) void fused_kernel(
    const float* __restrict__ x, const float* __restrict__ cb,
    const float* __restrict__ W, const float* __restrict__ bias,
    const float* __restrict__ u, const float* __restrict__ v,
    const float* __restrict__ rn, float* __restrict__ out,
    size_t idx_off, size_t val_off)
{
    __shared__ __align__(16) float uA[128 * TSTR];   // x+W tiles | reg tile | sims dump
    __shared__ __align__(16) float xeL[64 * XESTR];  // xe chunk [64][64]
    __shared__ float rnL[128];
    __shared__ float xnL[64];
    __shared__ unsigned char idxL[64 * 3];

    const int tid = threadIdx.x;
    const int tlo = tid & 15;
    const int thi = tid >> 4;
    const int row0 = blockIdx.x << 6;

    if (tid < 128) rnL[tid] = rn[tid];

    const int srow = tid >> 2;          // staging: 0..63
    const int scol = (tid & 3) << 4;    // 0,16,32,48

    float m2[4][8];                      // sims accumulators: rows tlo+16i, regs thi+16j
#pragma unroll
    for (int i = 0; i < 4; ++i)
#pragma unroll
        for (int j = 0; j < 8; ++j) m2[i][j] = 0.f;
    float nacc = 0.f;                    // |xe_row|^2 for tid<64 (exact round-2 order)

    for (int dc = 0; dc < 8; ++dc) {
        float m1[4][4];                  // xe accumulators: rows thi+16i, dims tlo+16j
#pragma unroll
        for (int i = 0; i < 4; ++i)
#pragma unroll
            for (int j = 0; j < 4; ++j) m1[i][j] = 0.f;

        for (int kc = 0; kc < 8; ++kc) {
            __syncthreads();
            {
                const float4* gx = (const float4*)(x + (size_t)(row0 + srow) * 512 + kc * 64 + scol);
                const float4* gw = (const float4*)(W + (size_t)(dc * 64 + srow) * 512 + kc * 64 + scol);
                float4* dx = (float4*)&uA[srow * TSTR + scol];
                float4* dw = (float4*)&uA[64 * TSTR + srow * TSTR + scol];
#pragma unroll
                for (int m = 0; m < 4; ++m) { dx[m] = gx[m]; dw[m] = gw[m]; }
            }
            __syncthreads();
            float s1[4][4];              // per-k-chunk sub-accumulator (accuracy)
#pragma unroll
            for (int i = 0; i < 4; ++i)
#pragma unroll
                for (int j = 0; j < 4; ++j) s1[i][j] = 0.f;
#pragma unroll
            for (int kk = 0; kk < 16; ++kk) {
                float4 xa[4], wa[4];
#pragma unroll
                for (int i = 0; i < 4; ++i)
                    xa[i] = *(const float4*)&uA[(thi + 16 * i) * TSTR + (kk << 2)];
#pragma unroll
                for (int j = 0; j < 4; ++j)
                    wa[j] = *(const float4*)&uA[64 * TSTR + (tlo + 16 * j) * TSTR + (kk << 2)];
#pragma unroll
                for (int i = 0; i < 4; ++i)
#pragma unroll
                    for (int j = 0; j < 4; ++j) {
                        s1[i][j] = fmaf(xa[i].x, wa[j].x, s1[i][j]);
                        s1[i][j] = fmaf(xa[i].y, wa[j].y, s1[i][j]);
                        s1[i][j] = fmaf(xa[i].z, wa[j].z, s1[i][j]);
                        s1[i][j] = fmaf(xa[i].w, wa[j].w, s1[i][j]);
                    }
            }
#pragma unroll
            for (int i = 0; i < 4; ++i)
#pragma unroll
                for (int j = 0; j < 4; ++j) m1[i][j] += s1[i][j];
        }
        // bias + store xe chunk to LDS (verbatim)
#pragma unroll
        for (int j = 0; j < 4; ++j) {
            float bj = bias[dc * 64 + tlo + 16 * j];
#pragma unroll
            for (int i = 0; i < 4; ++i)
                xeL[(thi + 16 * i) * XESTR + tlo + 16 * j] = m1[i][j] + bj;
        }
        __syncthreads();
        // stage codebook tile [128][64] into uA; norm pass (exact round-2 order)
        {
            const float4* gr = (const float4*)(cb + (size_t)(tid >> 1) * 512 + dc * 64 + ((tid & 1) << 5));
            float4* dr = (float4*)&uA[(tid >> 1) * TSTR + ((tid & 1) << 5)];
#pragma unroll
            for (int m = 0; m < 8; ++m) dr[m] = gr[m];
        }
        if (tid < 64) {
#pragma unroll
            for (int dd = 0; dd < 16; ++dd) {
                float4 q = *(const float4*)&xeL[tid * XESTR + (dd << 2)];
                nacc = fmaf(q.x, q.x, nacc);
                nacc = fmaf(q.y, q.y, nacc);
                nacc = fmaf(q.z, q.z, nacc);
                nacc = fmaf(q.w, q.w, nacc);
            }
        }
        __syncthreads();
        // phase 2: sims partial over this d-chunk (verbatim)
        float s2[4][8];
#pragma unroll
        for (int i = 0; i < 4; ++i)
#pragma unroll
            for (int j = 0; j < 8; ++j) s2[i][j] = 0.f;
#pragma unroll
        for (int dd = 0; dd < 16; ++dd) {
            float4 xv[4], rv[8];
#pragma unroll
            for (int i = 0; i < 4; ++i)
                xv[i] = *(const float4*)&xeL[(tlo + 16 * i) * XESTR + (dd << 2)];
#pragma unroll
            for (int j = 0; j < 8; ++j)
                rv[j] = *(const float4*)&uA[(thi + 16 * j) * TSTR + (dd << 2)];
#pragma unroll
            for (int i = 0; i < 4; ++i)
#pragma unroll
                for (int j = 0; j < 8; ++j) {
                    s2[i][j] = fmaf(xv[i].x, rv[j].x, s2[i][j]);
                    s2[i][j] = fmaf(xv[i].y, rv[j].y, s2[i][j]);
                    s2[i][j] = fmaf(xv[i].z, rv[j].z, s2[i][j]);
                    s2[i][j] = fmaf(xv[i].w, rv[j].w, s2[i][j]);
                }
        }
#pragma unroll
        for (int i = 0; i < 4; ++i)
#pragma unroll
            for (int j = 0; j < 8; ++j) m2[i][j] += s2[i][j];
    }
    __syncthreads();
    // dump sims numerators to LDS (verbatim addresses/values)
#pragma unroll
    for (int i = 0; i < 4; ++i)
#pragma unroll
        for (int j = 0; j < 8; ++j)
            uA[(tlo + 16 * i) * SSTR + thi + 16 * j] = m2[i][j];
    if (tid < 64) xnL[tid] = sqrtf(nacc);      // same sqrtf bits as round 2
    __syncthreads();

    // parallel top-3: 4 threads per row, packed keys replicate serial tie semantics
    {
        const int row = tid >> 2;
        const int p   = tid & 3;
        const float xn = xnL[row];
        unsigned long long a0 = 0, a1 = 0, a2 = 0;
#pragma unroll
        for (int t = 0; t < 32; ++t) {
            const int c = p + 4 * t;
            float s = uA[row * SSTR + c] / fmaxf(xn * rnL[c], 1e-8f);
            ins3(pack_key(s, c), a0, a1, a2);
        }
#pragma unroll
        for (int mask = 1; mask <= 2; mask <<= 1) {
            unsigned long long b0 = __shfl_xor(a0, mask);
            unsigned long long b1 = __shfl_xor(a1, mask);
            unsigned long long b2 = __shfl_xor(a2, mask);
            ins3(b0, a0, a1, a2); ins3(b1, a0, a1, a2); ins3(b2, a0, a1, a2);
        }
        if (p == 0) {
            const size_t g = (size_t)(row0 + row);
            float* oi = out + idx_off + g * 3;
            float* ov = out + val_off + g * 3;
            oi[0] = (float)key_col(a0); oi[1] = (float)key_col(a1); oi[2] = (float)key_col(a2);
            ov[0] = key_val(a0); ov[1] = key_val(a1); ov[2] = key_val(a2);
            idxL[row * 3 + 0] = (unsigned char)key_col(a0);
            idxL[row * 3 + 1] = (unsigned char)key_col(a1);
            idxL[row * 3 + 2] = (unsigned char)key_col(a2);
        }
    }
    __syncthreads();

    // adapted_centers = cb[idx] + u[tt]*v  (768 tasks over 256 threads)
    const float uu0 = u[0], uu1 = u[1], uu2 = u[2];
#pragma unroll
    for (int q = 0; q < 3; ++q) {
        int task = tid + 256 * q;            // 0..767 = 64 rows * 3 tt * 4 seg
        int row = task / 12;
        int rem = task - row * 12;
        int tt  = rem >> 2;
        int seg = rem & 3;
        int idx = idxL[row * 3 + tt];
        float uu = (tt == 0) ? uu0 : ((tt == 1) ? uu1 : uu2);
        const float4* gr4 = (const float4*)(cb + (size_t)idx * 512 + seg * 128);
        const float4* gv4 = (const float4*)(v + seg * 128);
        float4* ob = (float4*)(out + ((size_t)(row0 + row) * 3 + tt) * 512 + seg * 128);
#pragma unroll
        for (int c2 = 0; c2 < 32; ++c2) {
            float4 rv = gr4[c2];
            float4 vv = gv4[c2];
            float4 o;
            o.x = fmaf(uu, vv.x, rv.x);
            o.y = fmaf(uu, vv.y, rv.y);
            o.z = fmaf(uu, vv.z, rv.z);
            o.w = fmaf(uu, vv.w, rv.w);
            ob[c2] = o;
        }
    }
}

extern "C" void kernel_launch(void* const* d_in, const int* in_sizes, int n_in,
                              void* d_out, int out_size, void* d_ws, size_t ws_size,
                              hipStream_t stream) {
    const float* x  = (const float*)d_in[0];
    const float* cb = (const float*)d_in[1];
    const float* W  = (const float*)d_in[2];
    const float* b  = (const float*)d_in[3];
    const float* u  = (const float*)d_in[4];
    const float* v  = (const float*)d_in[5];
    float* rn = (float*)d_ws;                        // 128 floats scratch
    float* out = (float*)d_out;

    const size_t B = (size_t)in_sizes[0] / 512;      // 131072
    const size_t val_off = (size_t)out_size - 3 * B; // top_k_values
    const size_t idx_off = (size_t)out_size - 6 * B; // top_k_indices

    hipLaunchKernelGGL(rn_kernel, dim3(128), dim3(64), 0, stream, cb, rn);
    hipLaunchKernelGGL(fused_kernel, dim3((unsigned)(B / 64)), dim3(256), 0, stream,
                       x, cb, W, b, u, v, rn, out, idx_off, val_off);
}